// Round 1
// baseline (219.690 us; speedup 1.0000x reference)
//
#include <hip/hip_runtime.h>
#include <math.h>

#define BB   32
#define CC   512
#define NPIX 1600
#define KK   64
#define EPSF 1e-12f

// ---------------------------------------------------------------------------
// Stage 1: per-pixel inverse L2 norm over channels.  invn[b*N+n]
// ---------------------------------------------------------------------------
__global__ __launch_bounds__(256) void k_invnorm(const float* __restrict__ x,
                                                 float* __restrict__ invn) {
    int idx = blockIdx.x * 256 + threadIdx.x;      // b*NPIX + n  (exact grid)
    int b = idx / NPIX, n = idx - b * NPIX;
    const float* xp = x + (size_t)b * CC * NPIX + n;
    float ss = 0.f;
#pragma unroll 8
    for (int c = 0; c < CC; ++c) {
        float v = xp[(size_t)c * NPIX];
        ss = fmaf(v, v, ss);
    }
    invn[idx] = 1.f / fmaxf(sqrtf(ss), EPSF);
}

// ---------------------------------------------------------------------------
// Stage 2: logits[b,k,n] = invn[b,n] * sum_c w[k,c]*x[b,c,n]
// Tiled VALU GEMM: block = 256 thr computes [K=64, 64n] tile for one b.
// ---------------------------------------------------------------------------
__global__ __launch_bounds__(256) void k_logits(const float* __restrict__ x,
                                                const float* __restrict__ w,
                                                const float* __restrict__ invn,
                                                float* __restrict__ logits) {
    int n0 = blockIdx.x * 64;     // 25 tiles
    int b  = blockIdx.y;
    __shared__ __align__(16) float Xs[32 * 64];   // [cc][nn]
    __shared__ __align__(16) float Ws[32 * 68];   // [cc][k], pad 68 (16B-aligned rows)
    int t  = threadIdx.x;
    int tn = t & 15, tk = t >> 4;
    float acc[4][4] = {};
    const float* xb = x + (size_t)b * CC * NPIX;

    for (int c0 = 0; c0 < CC; c0 += 32) {
#pragma unroll
        for (int i = 0; i < 8; ++i) {
            int lid = i * 256 + t;
            int cc = lid >> 6, nn = lid & 63;
            Xs[cc * 64 + nn] = xb[(size_t)(c0 + cc) * NPIX + n0 + nn];
        }
#pragma unroll
        for (int i = 0; i < 8; ++i) {
            int lid = i * 256 + t;
            int cc = lid & 31, k = lid >> 5;
            Ws[cc * 68 + k] = w[k * CC + c0 + cc];
        }
        __syncthreads();
#pragma unroll
        for (int cc = 0; cc < 32; ++cc) {
            float4 wv = *reinterpret_cast<const float4*>(&Ws[cc * 68 + 4 * tk]);
            float4 xv = *reinterpret_cast<const float4*>(&Xs[cc * 64 + 4 * tn]);
            float wa[4] = {wv.x, wv.y, wv.z, wv.w};
            float xa[4] = {xv.x, xv.y, xv.z, xv.w};
#pragma unroll
            for (int i = 0; i < 4; ++i)
#pragma unroll
                for (int j = 0; j < 4; ++j)
                    acc[i][j] = fmaf(wa[i], xa[j], acc[i][j]);
        }
        __syncthreads();
    }

    float iv[4];
#pragma unroll
    for (int j = 0; j < 4; ++j) iv[j] = invn[b * NPIX + n0 + 4 * tn + j];
#pragma unroll
    for (int i = 0; i < 4; ++i) {
        int k = 4 * tk + i;
        float4 o = make_float4(acc[i][0] * iv[0], acc[i][1] * iv[1],
                               acc[i][2] * iv[2], acc[i][3] * iv[3]);
        *reinterpret_cast<float4*>(
            &logits[((size_t)(b * KK + k)) * NPIX + n0 + 4 * tn]) = o;
    }
}

// ---------------------------------------------------------------------------
// Stage 3: softmax over k (K=64) per (b,n); in-place on logits -> a
// ---------------------------------------------------------------------------
__global__ __launch_bounds__(256) void k_softmax(float* __restrict__ logits) {
    int idx = blockIdx.x * 256 + threadIdx.x;      // b*NPIX + n
    int b = idx / NPIX, n = idx - b * NPIX;
    float* lp = logits + (size_t)b * KK * NPIX + n;
    float v[KK];
    float m = -1e30f;
#pragma unroll
    for (int k = 0; k < KK; ++k) {
        v[k] = lp[(size_t)k * NPIX];
        m = fmaxf(m, v[k]);
    }
    float s = 0.f;
#pragma unroll
    for (int k = 0; k < KK; ++k) {
        v[k] = expf(v[k] - m);
        s += v[k];
    }
    float inv = 1.f / s;
#pragma unroll
    for (int k = 0; k < KK; ++k) lp[(size_t)k * NPIX] = v[k] * inv;
}

// ---------------------------------------------------------------------------
// Stage 4: asum[b,k] = sum_n a[b,k,n]
// ---------------------------------------------------------------------------
__global__ __launch_bounds__(256) void k_asum(const float* __restrict__ a,
                                              float* __restrict__ asum) {
    int row = blockIdx.x;                          // b*KK + k
    const float* ap = a + (size_t)row * NPIX;
    int t = threadIdx.x;
    float s = 0.f;
    for (int n = t; n < NPIX; n += 256) s += ap[n];
#pragma unroll
    for (int off = 32; off; off >>= 1) s += __shfl_down(s, off, 64);
    __shared__ float red[4];
    if ((t & 63) == 0) red[t >> 6] = s;
    __syncthreads();
    if (t == 0) asum[row] = red[0] + red[1] + red[2] + red[3];
}

// ---------------------------------------------------------------------------
// Stage 5: vlad_raw[b,k,c] = sum_n a[b,k,n] * invn[b,n] * x[b,c,n]  -> d_out
// Tiled VALU GEMM: block computes [K=64, 64c] tile for one b, loop n by 32.
// ---------------------------------------------------------------------------
__global__ __launch_bounds__(256) void k_vlad(const float* __restrict__ a,
                                              const float* __restrict__ x,
                                              const float* __restrict__ invn,
                                              float* __restrict__ vlad) {
    int c0 = blockIdx.x * 64;    // 8 tiles
    int b  = blockIdx.y;
    __shared__ __align__(16) float As[32 * 68];   // [nn][k]
    __shared__ __align__(16) float Xs[32 * 68];   // [nn][cc]
    int t  = threadIdx.x;
    int tc = t & 15, tk = t >> 4;
    float acc[4][4] = {};
    const float* ab  = a + (size_t)b * KK * NPIX;
    const float* xb  = x + (size_t)b * CC * NPIX;
    const float* ivb = invn + b * NPIX;

    for (int n0 = 0; n0 < NPIX; n0 += 32) {
#pragma unroll
        for (int i = 0; i < 8; ++i) {
            int lid = i * 256 + t;
            int nn = lid & 31, k = lid >> 5;
            As[nn * 68 + k] = ab[(size_t)k * NPIX + n0 + nn];
        }
#pragma unroll
        for (int i = 0; i < 8; ++i) {
            int lid = i * 256 + t;
            int nn = lid & 31, cc = lid >> 5;
            Xs[nn * 68 + cc] = xb[(size_t)(c0 + cc) * NPIX + n0 + nn] * ivb[n0 + nn];
        }
        __syncthreads();
#pragma unroll
        for (int nn = 0; nn < 32; ++nn) {
            float4 av = *reinterpret_cast<const float4*>(&As[nn * 68 + 4 * tk]);
            float4 xv = *reinterpret_cast<const float4*>(&Xs[nn * 68 + 4 * tc]);
            float aa[4] = {av.x, av.y, av.z, av.w};
            float xa[4] = {xv.x, xv.y, xv.z, xv.w};
#pragma unroll
            for (int i = 0; i < 4; ++i)
#pragma unroll
                for (int j = 0; j < 4; ++j)
                    acc[i][j] = fmaf(aa[i], xa[j], acc[i][j]);
        }
        __syncthreads();
    }
#pragma unroll
    for (int i = 0; i < 4; ++i) {
        int k = 4 * tk + i;
        float4 o = make_float4(acc[i][0], acc[i][1], acc[i][2], acc[i][3]);
        *reinterpret_cast<float4*>(
            &vlad[((size_t)(b * KK + k)) * CC + c0 + 4 * tc]) = o;
    }
}

// ---------------------------------------------------------------------------
// Stage 6: subtract asum*centroid, intra-normalize per (b,k) over C, in place
// on d_out; accumulate per-b sum of squares of the normalized rows.
// ---------------------------------------------------------------------------
__global__ __launch_bounds__(256) void k_intra(float* __restrict__ out,
                                               const float* __restrict__ asum,
                                               const float* __restrict__ cent,
                                               float* __restrict__ bsum) {
    int row = blockIdx.x;                          // b*KK + k
    int b = row >> 6, k = row & 63;
    int t = threadIdx.x;
    float as = asum[row];
    float v0 = out[(size_t)row * CC + t]       - as * cent[k * CC + t];
    float v1 = out[(size_t)row * CC + t + 256] - as * cent[k * CC + t + 256];
    float ss = v0 * v0 + v1 * v1;
#pragma unroll
    for (int off = 32; off; off >>= 1) ss += __shfl_down(ss, off, 64);
    __shared__ float red[4];
    __shared__ float s_inv;
    if ((t & 63) == 0) red[t >> 6] = ss;
    __syncthreads();
    if (t == 0) {
        float s = red[0] + red[1] + red[2] + red[3];
        float inv = 1.f / fmaxf(sqrtf(s), EPSF);
        s_inv = inv;
        atomicAdd(&bsum[b], s * inv * inv);
    }
    __syncthreads();
    float inv = s_inv;
    out[(size_t)row * CC + t]       = v0 * inv;
    out[(size_t)row * CC + t + 256] = v1 * inv;
}

// ---------------------------------------------------------------------------
// Stage 7: global L2 normalize per b over K*C
// ---------------------------------------------------------------------------
__global__ __launch_bounds__(256) void k_scale(float* __restrict__ out,
                                               const float* __restrict__ bsum) {
    int idx = blockIdx.x * 256 + threadIdx.x;      // over B*K*C, exact grid
    int b = idx >> 15;                             // K*C = 32768
    out[idx] *= 1.f / fmaxf(sqrtf(bsum[b]), EPSF);
}

// ---------------------------------------------------------------------------
extern "C" void kernel_launch(void* const* d_in, const int* in_sizes, int n_in,
                              void* d_out, int out_size, void* d_ws, size_t ws_size,
                              hipStream_t stream) {
    const float* x    = (const float*)d_in[0];   // [B,C,H,W]
    const float* cent = (const float*)d_in[1];   // [K,C]
    const float* w    = (const float*)d_in[2];   // [K,C]
    float* out = (float*)d_out;                  // [B, K*C] ; also vlad_raw scratch

    float* ws     = (float*)d_ws;
    float* invn   = ws;                          // B*NPIX           = 51200
    float* logits = ws + 51200;                  // B*KK*NPIX        = 3276800 (also a)
    float* asum   = ws + 51200 + 3276800;        // B*KK             = 2048
    float* bsum   = ws + 51200 + 3276800 + 2048; // B                = 32

    hipMemsetAsync(bsum, 0, BB * sizeof(float), stream);

    k_invnorm<<<dim3((BB * NPIX) / 256), 256, 0, stream>>>(x, invn);
    k_logits <<<dim3(NPIX / 64, BB), 256, 0, stream>>>(x, w, invn, logits);
    k_softmax<<<dim3((BB * NPIX) / 256), 256, 0, stream>>>(logits);
    k_asum   <<<dim3(BB * KK), 256, 0, stream>>>(logits, asum);
    k_vlad   <<<dim3(CC / 64, BB), 256, 0, stream>>>(logits, x, invn, out);
    k_intra  <<<dim3(BB * KK), 256, 0, stream>>>(out, asum, cent, bsum);
    k_scale  <<<dim3((BB * KK * CC) / 256), 256, 0, stream>>>(out, bsum);
}

// Round 2
// 162.781 us; speedup vs baseline: 1.3496x; 1.3496x over previous
//
#include <hip/hip_runtime.h>
#include <math.h>

#define BB   32
#define CC   512
#define NPIX 1600
#define KK   64
#define NT   25        // 64-wide n-tiles in k_fused
#define EPSF 1e-12f

// ---------------------------------------------------------------------------
// k_fused: per (n-tile of 64, b):
//   logits[k,n] = sum_c w[k,c] x[b,c,n]     (VALU GEMM, 64k x 64n, c-loop)
//   ssq[n]     += x^2 (free during GEMM; per-thread, duplicated across tg)
//   invn[n]     = 1/max(sqrt(ssq),eps)  -> global
//   a[k,n]      = softmax_k(logits*invn) -> a_t[b][n][k] (transposed!)
//   asum_p[b,k,tile] = sum_n a[k,n]      (per-tile partial)
// 256 thr: tn=t&15 (4 n each), tg=t>>4 (4 k each: k=tg*4+i)
// ---------------------------------------------------------------------------
__global__ __launch_bounds__(256) void k_fused(const float* __restrict__ x,
                                               const float* __restrict__ w,
                                               float* __restrict__ a_t,
                                               float* __restrict__ invn,
                                               float* __restrict__ asum_p) {
    int tile = blockIdx.x;          // 0..24
    int b    = blockIdx.y;
    int n0   = tile * 64;
    __shared__ __align__(16) float Xs[32 * 64];   // [cc][nn]
    __shared__ __align__(16) float Ws[32 * 68];   // [cc][k] pad 68 (272B rows, 16B-aligned)
    __shared__ __align__(16) float red[16 * 64];  // softmax tree buffer
    int t  = threadIdx.x;
    int tn = t & 15, tg = t >> 4;
    const float* xb = x + (size_t)b * CC * NPIX;
    float acc[4][4] = {};
    float ss[4] = {};

    for (int c0 = 0; c0 < CC; c0 += 32) {
#pragma unroll
        for (int i = 0; i < 2; ++i) {              // X: 512 float4 / 256 thr
            int q = i * 256 + t;
            int cc = q >> 4, n4 = q & 15;
            *(float4*)&Xs[cc * 64 + n4 * 4] =
                *(const float4*)&xb[(size_t)(c0 + cc) * NPIX + n0 + n4 * 4];
        }
#pragma unroll
        for (int i = 0; i < 8; ++i) {              // W: transposed scalar stage
            int lid = i * 256 + t;
            int cc = lid & 31, k = lid >> 5;
            Ws[cc * 68 + k] = w[(size_t)k * CC + c0 + cc];
        }
        __syncthreads();
#pragma unroll
        for (int cc = 0; cc < 32; ++cc) {
            float4 wv = *(const float4*)&Ws[cc * 68 + tg * 4];
            float4 xv = *(const float4*)&Xs[cc * 64 + tn * 4];
            float wa[4] = {wv.x, wv.y, wv.z, wv.w};
            float xa[4] = {xv.x, xv.y, xv.z, xv.w};
#pragma unroll
            for (int j = 0; j < 4; ++j) ss[j] = fmaf(xa[j], xa[j], ss[j]);
#pragma unroll
            for (int i = 0; i < 4; ++i)
#pragma unroll
                for (int j = 0; j < 4; ++j)
                    acc[i][j] = fmaf(wa[i], xa[j], acc[i][j]);
        }
        __syncthreads();
    }

    float iv[4];
#pragma unroll
    for (int j = 0; j < 4; ++j) iv[j] = 1.f / fmaxf(sqrtf(ss[j]), EPSF);
    if (tg == 0) {
#pragma unroll
        for (int j = 0; j < 4; ++j) invn[b * NPIX + n0 + tn * 4 + j] = iv[j];
    }

    // logits + local max
    float l[4][4], lm[4];
#pragma unroll
    for (int j = 0; j < 4; ++j) {
#pragma unroll
        for (int i = 0; i < 4; ++i) l[i][j] = acc[i][j] * iv[j];
        lm[j] = fmaxf(fmaxf(l[0][j], l[1][j]), fmaxf(l[2][j], l[3][j]));
    }
    *(float4*)&red[tg * 64 + tn * 4] = make_float4(lm[0], lm[1], lm[2], lm[3]);
    __syncthreads();
#pragma unroll
    for (int off = 8; off >= 1; off >>= 1) {
        if (tg < off) {
#pragma unroll
            for (int j = 0; j < 4; ++j) {
                int idx = tg * 64 + tn * 4 + j;
                red[idx] = fmaxf(red[idx], red[(tg + off) * 64 + tn * 4 + j]);
            }
        }
        __syncthreads();
    }
    float m[4];
#pragma unroll
    for (int j = 0; j < 4; ++j) m[j] = red[tn * 4 + j];
    __syncthreads();

    float e[4][4], ls[4];
#pragma unroll
    for (int j = 0; j < 4; ++j) {
        ls[j] = 0.f;
#pragma unroll
        for (int i = 0; i < 4; ++i) {
            e[i][j] = expf(l[i][j] - m[j]);
            ls[j] += e[i][j];
        }
    }
    *(float4*)&red[tg * 64 + tn * 4] = make_float4(ls[0], ls[1], ls[2], ls[3]);
    __syncthreads();
#pragma unroll
    for (int off = 8; off >= 1; off >>= 1) {
        if (tg < off) {
#pragma unroll
            for (int j = 0; j < 4; ++j) {
                int idx = tg * 64 + tn * 4 + j;
                red[idx] += red[(tg + off) * 64 + tn * 4 + j];
            }
        }
        __syncthreads();
    }

    float p[4] = {};
#pragma unroll
    for (int j = 0; j < 4; ++j) {
        float sd = 1.f / red[tn * 4 + j];
        float4 o = make_float4(e[0][j] * sd, e[1][j] * sd, e[2][j] * sd, e[3][j] * sd);
        *(float4*)&a_t[((size_t)b * NPIX + n0 + tn * 4 + j) * KK + tg * 4] = o;
        p[0] += o.x; p[1] += o.y; p[2] += o.z; p[3] += o.w;
    }
#pragma unroll
    for (int off = 1; off < 16; off <<= 1) {
#pragma unroll
        for (int i = 0; i < 4; ++i) p[i] += __shfl_xor(p[i], off, 64);
    }
    if (tn == 0) {
#pragma unroll
        for (int i = 0; i < 4; ++i)
            asum_p[((size_t)b * KK + tg * 4 + i) * NT + tile] = p[i];
    }
}

// ---------------------------------------------------------------------------
// k_vlad: part[s][b][k][c] = sum_{n in chunk s} a[k,n] * invn[n] * x[c,n]
// grid (4 c-tiles of 128, NS, 32 b), 256 thr: tc=t&31 (4 c), tg=t>>5 (8 k)
// ---------------------------------------------------------------------------
__global__ __launch_bounds__(256) void k_vlad(const float* __restrict__ a_t,
                                              const float* __restrict__ x,
                                              const float* __restrict__ invn,
                                              float* __restrict__ part,
                                              int nchunk) {
    int c0 = blockIdx.x * 128;
    int s  = blockIdx.y;
    int b  = blockIdx.z;
    __shared__ __align__(16) float As[32 * 64];    // [nn][k]  (stride-1 writes)
    __shared__ __align__(16) float Xs[32 * 132];   // [nn][cc] pad 132
    int t  = threadIdx.x;
    int tc = t & 31, tg = t >> 5;
    float acc[8][4] = {};
    const float* ab  = a_t + (size_t)b * NPIX * KK;
    const float* xb  = x + (size_t)b * CC * NPIX;
    const float* ivb = invn + b * NPIX;
    int nbase = s * nchunk;

    for (int n0 = nbase; n0 < nbase + nchunk; n0 += 32) {
#pragma unroll
        for (int i = 0; i < 2; ++i) {              // A: 512 float4, stride-1 LDS
            int q = i * 256 + t;
            int nn = q >> 4, k4 = q & 15;
            *(float4*)&As[nn * 64 + k4 * 4] =
                *(const float4*)&ab[(size_t)(n0 + nn) * KK + k4 * 4];
        }
#pragma unroll
        for (int i = 0; i < 4; ++i) {              // X: transpose + invn scale
            int q = i * 256 + t;                   // 1024 float4 over n
            int cc = q >> 3, n4 = q & 7;
            float4 xv  = *(const float4*)&xb[(size_t)(c0 + cc) * NPIX + n0 + n4 * 4];
            float4 ivv = *(const float4*)&ivb[n0 + n4 * 4];
            Xs[(n4 * 4 + 0) * 132 + cc] = xv.x * ivv.x;
            Xs[(n4 * 4 + 1) * 132 + cc] = xv.y * ivv.y;
            Xs[(n4 * 4 + 2) * 132 + cc] = xv.z * ivv.z;
            Xs[(n4 * 4 + 3) * 132 + cc] = xv.w * ivv.w;
        }
        __syncthreads();
#pragma unroll 8
        for (int nn = 0; nn < 32; ++nn) {
            float4 a0 = *(const float4*)&As[nn * 64 + tg * 8];
            float4 a1 = *(const float4*)&As[nn * 64 + tg * 8 + 4];
            float4 xv = *(const float4*)&Xs[nn * 132 + tc * 4];
            float aa[8] = {a0.x, a0.y, a0.z, a0.w, a1.x, a1.y, a1.z, a1.w};
            float xa[4] = {xv.x, xv.y, xv.z, xv.w};
#pragma unroll
            for (int i = 0; i < 8; ++i)
#pragma unroll
                for (int j = 0; j < 4; ++j)
                    acc[i][j] = fmaf(aa[i], xa[j], acc[i][j]);
        }
        __syncthreads();
    }
#pragma unroll
    for (int i = 0; i < 8; ++i) {
        int k = tg * 8 + i;
        *(float4*)&part[(((size_t)s * BB + b) * KK + k) * CC + c0 + tc * 4] =
            make_float4(acc[i][0], acc[i][1], acc[i][2], acc[i][3]);
    }
}

// ---------------------------------------------------------------------------
// k_intra: sum NS partials, asum from 25 tile-partials, subtract asum*cent,
// intra-normalize per (b,k), accumulate per-b sum of squares.
// ---------------------------------------------------------------------------
__global__ __launch_bounds__(256) void k_intra(const float* __restrict__ part, int ns,
                                               const float* __restrict__ asum_p,
                                               const float* __restrict__ cent,
                                               float* __restrict__ out,
                                               float* __restrict__ bsum) {
    int row = blockIdx.x;                          // b*KK + k
    int b = row >> 6, k = row & 63;
    int t = threadIdx.x;
    float v0 = 0.f, v1 = 0.f;
    for (int s2 = 0; s2 < ns; ++s2) {
        const float* p = part + (((size_t)s2 * BB + b) * KK + k) * CC;
        v0 += p[t];
        v1 += p[t + 256];
    }
    float as = 0.f;
#pragma unroll
    for (int i = 0; i < NT; ++i) as += asum_p[(size_t)row * NT + i];
    v0 -= as * cent[k * CC + t];
    v1 -= as * cent[k * CC + t + 256];
    float ssq = v0 * v0 + v1 * v1;
#pragma unroll
    for (int off = 32; off; off >>= 1) ssq += __shfl_down(ssq, off, 64);
    __shared__ float red[4];
    __shared__ float s_inv;
    if ((t & 63) == 0) red[t >> 6] = ssq;
    __syncthreads();
    if (t == 0) {
        float sm = red[0] + red[1] + red[2] + red[3];
        float inv = 1.f / fmaxf(sqrtf(sm), EPSF);
        s_inv = inv;
        atomicAdd(&bsum[b], sm * inv * inv);
    }
    __syncthreads();
    float inv = s_inv;
    out[(size_t)row * CC + t]       = v0 * inv;
    out[(size_t)row * CC + t + 256] = v1 * inv;
}

// ---------------------------------------------------------------------------
__global__ __launch_bounds__(256) void k_scale(float* __restrict__ out,
                                               const float* __restrict__ bsum) {
    int idx = blockIdx.x * 256 + threadIdx.x;      // B*K*C exact
    int b = idx >> 15;                             // K*C = 32768
    out[idx] *= 1.f / fmaxf(sqrtf(bsum[b]), EPSF);
}

// ---------------------------------------------------------------------------
extern "C" void kernel_launch(void* const* d_in, const int* in_sizes, int n_in,
                              void* d_out, int out_size, void* d_ws, size_t ws_size,
                              hipStream_t stream) {
    const float* x    = (const float*)d_in[0];   // [B,C,H,W]
    const float* cent = (const float*)d_in[1];   // [K,C]
    const float* w    = (const float*)d_in[2];   // [K,C]
    float* out = (float*)d_out;

    float* ws = (float*)d_ws;
    const size_t o_at   = 0;                         // B*N*K      = 3,276,800
    const size_t o_invn = 3276800;                   // B*N        =    51,200
    const size_t o_asum = o_invn + 51200;            // B*K*NT     =    51,200
    const size_t o_bsum = o_asum + 51200;            // B (+pad)   =        64
    const size_t o_part = o_bsum + 64;               // NS * B*K*C

    // pick NS (n-chunk count) that fits workspace; chunk must be mult of 32
    const size_t pelems = (size_t)BB * KK * CC;      // 1,048,576 per partial
    int ns = 0;
    const int cand[4] = {10, 5, 2, 1};
    for (int i = 0; i < 4; ++i) {
        if ((o_part + (size_t)cand[i] * pelems) * 4 <= ws_size) { ns = cand[i]; break; }
    }
    float* part = (ns > 0) ? (ws + o_part) : out;    // fallback: single partial in d_out
    if (ns == 0) ns = 1;
    int nchunk = NPIX / ns;

    hipMemsetAsync(ws + o_bsum, 0, BB * sizeof(float), stream);

    k_fused<<<dim3(NT, BB), 256, 0, stream>>>(x, w, ws + o_at, ws + o_invn, ws + o_asum);
    k_vlad <<<dim3(4, ns, BB), 256, 0, stream>>>(ws + o_at, x, ws + o_invn, part, nchunk);
    k_intra<<<dim3(BB * KK), 256, 0, stream>>>(part, ns, ws + o_asum, cent, out, ws + o_bsum);
    k_scale<<<dim3((BB * KK * CC) / 256), 256, 0, stream>>>(out, ws + o_bsum);
}